// Round 9
// baseline (224.046 us; speedup 1.0000x reference)
//
#include <hip/hip_runtime.h>

#define T_STEPS 301
#define IN_DIM  40
#define LOG2E   1.44269504088896340736f

typedef __attribute__((ext_vector_type(8))) _Float16 f16x8;
typedef __attribute__((ext_vector_type(4))) float f32x4;
typedef unsigned short ushort_t;
typedef unsigned int uint_t;

__device__ __forceinline__ f16x8 cvt8h(const float4 a, const float4 b) {
  f16x8 r;
  r[0] = (_Float16)a.x; r[1] = (_Float16)a.y; r[2] = (_Float16)a.z; r[3] = (_Float16)a.w;
  r[4] = (_Float16)b.x; r[5] = (_Float16)b.y; r[6] = (_Float16)b.z; r[7] = (_Float16)b.w;
  return r;
}

// z inputs pre-scaled by log2e (2*log2e for g-gate) -> exp2-based activations.
__device__ __forceinline__ float lstm_act(float zi, float zf, float zg, float zo, float& cc) {
  const float ig = __builtin_amdgcn_rcpf(1.0f + __builtin_amdgcn_exp2f(-zi));
  const float fg = __builtin_amdgcn_rcpf(1.0f + __builtin_amdgcn_exp2f(-zf));
  const float gg = 1.0f - 2.0f * __builtin_amdgcn_rcpf(1.0f + __builtin_amdgcn_exp2f(zg));
  const float og = __builtin_amdgcn_rcpf(1.0f + __builtin_amdgcn_exp2f(-zo));
  cc = fg * cc + ig * gg;
  const float tc = 1.0f - 2.0f * __builtin_amdgcn_rcpf(1.0f + __builtin_amdgcn_exp2f(cc * (2.0f * LOG2E)));
  return og * tc;
}

// 256 blocks x 256 thr = 1024 fully-INDEPENDENT waves (1/SIMD), NO barriers.
// Each wave: 4 batches, all 4 gates x 64 hidden = 16 D-tiles; rows = 4*batch + q
// (4-step time-packing, full M=16). One xproj volley per 4 steps into zacc;
// each step's recurrent MFMA adds h[t-1] only into rows with q==t&3 (A rows for
// other q are cndmask-zeroed). h exchange = 640B wave-private LDS scratch
// (write 4x u16, read 2x b128), ordered by in-wave lgkmcnt(0) only.
// Roles of lane l = 16*g16 + c15:
//   D/act: batch = g16, states n_j = 16j + c15 (j=0..3), reg = q
//   A:     row c15 -> (s_a = c15>>2, q_a = c15&3), k-chunk = g16
//   B:     col c15, k-chunk = g16
__global__ __launch_bounds__(256, 1)
void lstm_w1(const float* __restrict__ x, const float* __restrict__ w_ih,
             const float* __restrict__ w_hh, const float* __restrict__ b_ih,
             const float* __restrict__ b_hh, const float* __restrict__ w_clf,
             const float* __restrict__ b_clf, float* __restrict__ out) {
  __shared__ ushort_t hscr[4][4][80];   // [wave][batch][64 n + 16 pad] = 2.5 KB

  const int tid = threadIdx.x;
  const int l   = tid & 63;
  const int wv  = tid >> 6;
  const int c15 = l & 15;
  const int g16 = l >> 4;
  const int b0  = blockIdx.x * 16 + wv * 4;

  const float gsc[4] = {LOG2E, LOG2E, 2.0f * LOG2E, LOG2E};

  // ---- all weights in registers (fp16, prescaled by log2e) ----
  f16x8 whh[4][4][2], wih[4][4][2];
  float biasv[4][4];
#pragma unroll
  for (int g = 0; g < 4; ++g) {
    const float s = gsc[g];
#pragma unroll
    for (int j = 0; j < 4; ++j) {
      const int n = 16 * j + c15;
      const float* wr = w_hh + (size_t)(g * 64 + n) * 64;
#pragma unroll
      for (int kc = 0; kc < 2; ++kc) {
        float4 v0 = *(const float4*)(wr + kc * 32 + g16 * 8);
        float4 v1 = *(const float4*)(wr + kc * 32 + g16 * 8 + 4);
        v0.x *= s; v0.y *= s; v0.z *= s; v0.w *= s;
        v1.x *= s; v1.y *= s; v1.z *= s; v1.w *= s;
        whh[g][j][kc] = cvt8h(v0, v1);
      }
      const float* wi = w_ih + (size_t)(g * 64 + n) * IN_DIM;
      {
        float4 v0 = *(const float4*)(wi + g16 * 8);     // k = 8*g16..+8 <= 31
        float4 v1 = *(const float4*)(wi + g16 * 8 + 4);
        v0.x *= s; v0.y *= s; v0.z *= s; v0.w *= s;
        v1.x *= s; v1.y *= s; v1.z *= s; v1.w *= s;
        wih[g][j][0] = cvt8h(v0, v1);
      }
      {
        float4 v0 = make_float4(0, 0, 0, 0), v1 = make_float4(0, 0, 0, 0);
        if (g16 == 0) {                                 // k = 32..39
          v0 = *(const float4*)(wi + 32);
          v1 = *(const float4*)(wi + 36);
          v0.x *= s; v0.y *= s; v0.z *= s; v0.w *= s;
          v1.x *= s; v1.y *= s; v1.z *= s; v1.w *= s;
        }
        wih[g][j][1] = cvt8h(v0, v1);
      }
      biasv[g][j] = (b_ih[g * 64 + n] + b_hh[g * 64 + n]) * s;
    }
  }

  // zero this wave's scratch (h[-1] = 0); wave-private -> lgkmcnt only, no barrier
  for (int i = l; i < 320; i += 64) (&hscr[wv][0][0])[i] = 0;

  const int s_a = c15 >> 2, q_a = c15 & 3;
  const float* xb = x + (size_t)(b0 + s_a) * T_STEPS * IN_DIM;

  // initial x prefetch (pack 0: lane's time = q_a)
  float4 xa0 = *(const float4*)(xb + q_a * IN_DIM + g16 * 8);
  float4 xa1 = *(const float4*)(xb + q_a * IN_DIM + g16 * 8 + 4);
  float4 xq0 = make_float4(0, 0, 0, 0), xq1 = make_float4(0, 0, 0, 0);
  if (g16 == 0) {
    xq0 = *(const float4*)(xb + q_a * IN_DIM + 32);
    xq1 = *(const float4*)(xb + q_a * IN_DIM + 36);
  }

  f32x4 z[4][4];                     // zacc [gate][n-tile]
  float cc[4] = {0.f, 0.f, 0.f, 0.f};
  float acl[4] = {0.f, 0.f, 0.f, 0.f};
  float wcv[4];
#pragma unroll
  for (int j = 0; j < 4; ++j) wcv[j] = w_clf[16 * j + c15];   // t=0

  const f16x8* const rd0 = (const f16x8*)&hscr[wv][s_a][8 * g16];       // kc0
  const f16x8* const rd1 = (const f16x8*)&hscr[wv][s_a][32 + 8 * g16];  // kc1
  ushort_t* const wb = &hscr[wv][g16][0];

  asm volatile("s_waitcnt lgkmcnt(0)" ::: "memory");   // scratch zeros visible

#define RSTEP(Q, TCUR)                                                            \
  {                                                                               \
    f16x8 a0 = *rd0, a1 = *rd1;                                                   \
    const f16x8 fz = {};                                                          \
    if (q_a != (Q)) { a0 = fz; a1 = fz; }                                         \
    _Pragma("unroll")                                                             \
    for (int g = 0; g < 4; ++g) {                                                 \
      _Pragma("unroll")                                                           \
      for (int j = 0; j < 4; ++j) {                                               \
        z[g][j] = __builtin_amdgcn_mfma_f32_16x16x32_f16(a0, whh[g][j][0], z[g][j], 0, 0, 0); \
        z[g][j] = __builtin_amdgcn_mfma_f32_16x16x32_f16(a1, whh[g][j][1], z[g][j], 0, 0, 0); \
      }                                                                           \
    }                                                                             \
    float wcn[4];                                                                 \
    const int tn = ((TCUR) + 1 < T_STEPS) ? (TCUR) + 1 : (TCUR);                  \
    _Pragma("unroll")                                                             \
    for (int j = 0; j < 4; ++j) wcn[j] = w_clf[tn * 64 + 16 * j + c15];           \
    _Pragma("unroll")                                                             \
    for (int j = 0; j < 4; ++j) {                                                 \
      const float h = lstm_act(z[0][j][Q], z[1][j][Q], z[2][j][Q], z[3][j][Q], cc[j]); \
      acl[j] += h * wcv[j];                                                       \
      union { _Float16 hf; ushort_t u; } cv; cv.hf = (_Float16)h;                 \
      wb[16 * j + c15] = cv.u;                                                    \
    }                                                                             \
    _Pragma("unroll")                                                             \
    for (int j = 0; j < 4; ++j) wcv[j] = wcn[j];                                  \
    asm volatile("s_waitcnt lgkmcnt(0)" ::: "memory");                            \
  }

  for (int p = 0; p <= 75; ++p) {
    const int t0 = 4 * p;
    // ---- xproj volley: zacc = bias + x[t0..t0+3] @ w_ih^T  (full M=16) ----
    {
      const f16x8 xf0 = cvt8h(xa0, xa1);
      const f16x8 xf1 = cvt8h(xq0, xq1);
#pragma unroll
      for (int g = 0; g < 4; ++g) {
#pragma unroll
        for (int j = 0; j < 4; ++j) {
          f32x4 zz = {biasv[g][j], biasv[g][j], biasv[g][j], biasv[g][j]};
          zz = __builtin_amdgcn_mfma_f32_16x16x32_f16(xf0, wih[g][j][0], zz, 0, 0, 0);
          z[g][j] = __builtin_amdgcn_mfma_f32_16x16x32_f16(xf1, wih[g][j][1], zz, 0, 0, 0);
        }
      }
      if (t0 + 4 < T_STEPS) {   // prefetch x for next pack (in flight across steps)
        const int tq = t0 + 4 + q_a;
        const int tm = (tq <= T_STEPS - 1) ? tq : T_STEPS - 1;
        const float* xp = xb + (size_t)tm * IN_DIM + g16 * 8;
        xa0 = *(const float4*)xp;
        xa1 = *(const float4*)(xp + 4);
        if (g16 == 0) {
          xq0 = *(const float4*)(xb + (size_t)tm * IN_DIM + 32);
          xq1 = *(const float4*)(xb + (size_t)tm * IN_DIM + 36);
        }
      }
    }
    RSTEP(0, t0)
    if (t0 + 1 >= T_STEPS) break;   // t0 == 300 (uniform)
    RSTEP(1, t0 + 1)
    RSTEP(2, t0 + 2)
    RSTEP(3, t0 + 3)
  }
#undef RSTEP

  // ---- epilogue: in-wave reduce over the 16 c15-lanes of each batch group ----
  float a = acl[0] + acl[1] + acl[2] + acl[3];
  a += __shfl_xor(a, 1);
  a += __shfl_xor(a, 2);
  a += __shfl_xor(a, 4);
  a += __shfl_xor(a, 8);
  if (c15 == 0) out[b0 + g16] = a + b_clf[0];
}

extern "C" void kernel_launch(void* const* d_in, const int* in_sizes, int n_in,
                              void* d_out, int out_size, void* d_ws, size_t ws_size,
                              hipStream_t stream) {
  const float* x     = (const float*)d_in[0];
  const float* w_ih  = (const float*)d_in[1];
  const float* w_hh  = (const float*)d_in[2];
  const float* b_ih  = (const float*)d_in[3];
  const float* b_hh  = (const float*)d_in[4];
  const float* w_clf = (const float*)d_in[5];
  const float* b_clf = (const float*)d_in[6];
  float* out = (float*)d_out;

  lstm_w1<<<256, 256, 0, stream>>>(x, w_ih, w_hh, b_ih, b_hh, w_clf, b_clf, out);
}